// Round 1
// baseline (3982.345 us; speedup 1.0000x reference)
//
#include <hip/hip_runtime.h>

// ---------------------------------------------------------------------------
// 2-layer GCN forward (PyG GCNConv semantics, add_self_loops, sym-norm)
//   h   = relu( Agg(norm, x@W1) + dinv^2 * (x@W1) + b1 )
//   out = L2normalize( Agg(norm, h@W2) + dinv^2 * (h@W2) + b2 )
// norm[e] = dinv[src]*ew[e]*dinv[dst],  dinv = rsqrt(segsum(ew,dst)+1)
// ---------------------------------------------------------------------------

__global__ void k_deg(const int* __restrict__ dst, const float* __restrict__ ew,
                      float* __restrict__ deg, int E) {
    int i = blockIdx.x * 256 + threadIdx.x;
    if (i < E) unsafeAtomicAdd(&deg[dst[i]], ew[i]);
}

__global__ void k_dinv(float* __restrict__ deg, int N) {
    int i = blockIdx.x * 256 + threadIdx.x;
    if (i < N) deg[i] = rsqrtf(deg[i] + 1.0f);   // deg>=1 always
}

__global__ void k_edgenorm(const int* __restrict__ src, const int* __restrict__ dst,
                           const float* __restrict__ ew, const float* __restrict__ dinv,
                           float* __restrict__ enorm, int E) {
    int i = blockIdx.x * 256 + threadIdx.x;
    if (i < E) enorm[i] = dinv[src[i]] * ew[i] * dinv[dst[i]];
}

// GEMM1: xw1[N,128] = x[N,256] @ W1[256,128];  agg1 init = dinv^2 * xw1
// block = 256 threads, BM=64, BK=64, micro-tile 4x8 per thread.
__launch_bounds__(256)
__global__ void k_gemm1(const float* __restrict__ x, const float* __restrict__ W1,
                        const float* __restrict__ dinv,
                        float* __restrict__ xw1, float* __restrict__ agg1, int N) {
    __shared__ float As[64 * 68];    // stride 68 (pad, 16B-aligned rows)
    __shared__ float Bs[64 * 132];   // stride 132
    const int t  = threadIdx.x;
    const int tx = t & 15;           // col group (8 cols each)
    const int ty = t >> 4;           // row group (4 rows each)
    const int row0 = blockIdx.x * 64;

    float acc[4][8];
#pragma unroll
    for (int r = 0; r < 4; ++r)
#pragma unroll
        for (int c = 0; c < 8; ++c) acc[r][c] = 0.f;

    for (int kt = 0; kt < 4; ++kt) {
        // A tile: 64 rows x 64 cols = 1024 float4
#pragma unroll
        for (int i = 0; i < 4; ++i) {
            int flat = t + i * 256;
            int r = flat >> 4, c4 = flat & 15;
            int gr = row0 + r;
            float4 v = make_float4(0.f, 0.f, 0.f, 0.f);
            if (gr < N) v = *(const float4*)(x + (size_t)gr * 256 + kt * 64 + c4 * 4);
            *(float4*)(As + r * 68 + c4 * 4) = v;
        }
        // B tile: 64 rows x 128 cols = 2048 float4
#pragma unroll
        for (int i = 0; i < 8; ++i) {
            int flat = t + i * 256;
            int r = flat >> 5, c4 = flat & 31;
            float4 v = *(const float4*)(W1 + (size_t)(kt * 64 + r) * 128 + c4 * 4);
            *(float4*)(Bs + r * 132 + c4 * 4) = v;
        }
        __syncthreads();
#pragma unroll
        for (int k = 0; k < 64; ++k) {
            float a[4];
#pragma unroll
            for (int r = 0; r < 4; ++r) a[r] = As[(ty * 4 + r) * 68 + k];
            float4 b0 = *(const float4*)(Bs + k * 132 + tx * 8);
            float4 b1 = *(const float4*)(Bs + k * 132 + tx * 8 + 4);
#pragma unroll
            for (int r = 0; r < 4; ++r) {
                acc[r][0] += a[r] * b0.x; acc[r][1] += a[r] * b0.y;
                acc[r][2] += a[r] * b0.z; acc[r][3] += a[r] * b0.w;
                acc[r][4] += a[r] * b1.x; acc[r][5] += a[r] * b1.y;
                acc[r][6] += a[r] * b1.z; acc[r][7] += a[r] * b1.w;
            }
        }
        __syncthreads();
    }
#pragma unroll
    for (int r = 0; r < 4; ++r) {
        int gr = row0 + ty * 4 + r;
        if (gr >= N) continue;
        float di = dinv[gr];
        float d2 = di * di;
        float4 v0 = make_float4(acc[r][0], acc[r][1], acc[r][2], acc[r][3]);
        float4 v1 = make_float4(acc[r][4], acc[r][5], acc[r][6], acc[r][7]);
        float* xp = xw1 + (size_t)gr * 128 + tx * 8;
        float* ap = agg1 + (size_t)gr * 128 + tx * 8;
        *(float4*)(xp)     = v0;
        *(float4*)(xp + 4) = v1;
        float4 a0 = make_float4(d2 * v0.x, d2 * v0.y, d2 * v0.z, d2 * v0.w);
        float4 a1 = make_float4(d2 * v1.x, d2 * v1.y, d2 * v1.z, d2 * v1.w);
        *(float4*)(ap)     = a0;
        *(float4*)(ap + 4) = a1;
    }
}

// GEMM2: h = relu(agg1 + b1);  hw2[N,40] = h @ W2[128,40]
// epilogue: hw2 store + agg2 init = dinv^2*hw2 + b2
// block = 320 threads (5 waves), BM=64, full K=128 in one LDS tile.
__launch_bounds__(320)
__global__ void k_gemm2(const float* __restrict__ agg1, const float* __restrict__ W2,
                        const float* __restrict__ b1, const float* __restrict__ b2,
                        const float* __restrict__ dinv,
                        float* __restrict__ hw2, float* __restrict__ agg2, int N) {
    __shared__ float As[64 * 132];   // 64 rows x 128 cols (pad)
    __shared__ float Bs[128 * 40];
    const int t = threadIdx.x;
    const int row0 = blockIdx.x * 64;

    for (int flat = t; flat < 128 * 40; flat += 320) Bs[flat] = W2[flat];

#pragma unroll
    for (int i = 0; i < 7; ++i) {
        int flat = t + i * 320;
        if (flat < 2048) {
            int r = flat >> 5, c4 = flat & 31;
            int gr = row0 + r;
            float4 v = make_float4(0.f, 0.f, 0.f, 0.f);
            if (gr < N) {
                v = *(const float4*)(agg1 + (size_t)gr * 128 + c4 * 4);
                float4 bb = *(const float4*)(b1 + c4 * 4);
                v.x = fmaxf(v.x + bb.x, 0.f);
                v.y = fmaxf(v.y + bb.y, 0.f);
                v.z = fmaxf(v.z + bb.z, 0.f);
                v.w = fmaxf(v.w + bb.w, 0.f);
            }
            *(float4*)(As + r * 132 + c4 * 4) = v;
        }
    }
    __syncthreads();

    const int tx = t % 40;          // output col
    const int ty = t / 40;          // 0..7, 8 rows each
    float acc[8];
#pragma unroll
    for (int r = 0; r < 8; ++r) acc[r] = 0.f;
    for (int k = 0; k < 128; ++k) {
        float b = Bs[k * 40 + tx];
#pragma unroll
        for (int r = 0; r < 8; ++r) acc[r] += As[(ty * 8 + r) * 132 + k] * b;
    }
#pragma unroll
    for (int r = 0; r < 8; ++r) {
        int gr = row0 + ty * 8 + r;
        if (gr < N) {
            float di = dinv[gr];
            float v = acc[r];
            hw2[(size_t)gr * 40 + tx]  = v;
            agg2[(size_t)gr * 40 + tx] = di * di * v + b2[tx];
        }
    }
}

// Edge-parallel scatter: agg[dst] += norm[e] * feat[src], float4 chunks.
template <int CH4, int STRIDE>
__global__ void k_scatter(const int* __restrict__ src, const int* __restrict__ dst,
                          const float* __restrict__ enorm, const float* __restrict__ feat,
                          float* __restrict__ agg, int E) {
    const int total = E * CH4;
    for (int idx = blockIdx.x * blockDim.x + threadIdx.x; idx < total;
         idx += gridDim.x * blockDim.x) {
        int e = idx / CH4;
        int j = idx - e * CH4;
        float w = enorm[e];
        int s = src[e], d = dst[e];
        float4 v = *(const float4*)(feat + (size_t)s * STRIDE + j * 4);
        float* p = agg + (size_t)d * STRIDE + j * 4;
        unsafeAtomicAdd(p + 0, w * v.x);
        unsafeAtomicAdd(p + 1, w * v.y);
        unsafeAtomicAdd(p + 2, w * v.z);
        unsafeAtomicAdd(p + 3, w * v.w);
    }
}

// Row L2-normalize 40 floats -> d_out
__global__ void k_normalize(const float* __restrict__ agg2, float* __restrict__ out, int N) {
    int i = blockIdx.x * 256 + threadIdx.x;
    if (i >= N) return;
    const float4* p = (const float4*)(agg2 + (size_t)i * 40);
    float4 v[10];
    float s = 0.f;
#pragma unroll
    for (int j = 0; j < 10; ++j) {
        v[j] = p[j];
        s += v[j].x * v[j].x + v[j].y * v[j].y + v[j].z * v[j].z + v[j].w * v[j].w;
    }
    float nrm = sqrtf(s);
    float inv = 1.f / fmaxf(nrm, 1e-12f);
    float4* q = (float4*)(out + (size_t)i * 40);
#pragma unroll
    for (int j = 0; j < 10; ++j) {
        float4 o = make_float4(v[j].x * inv, v[j].y * inv, v[j].z * inv, v[j].w * inv);
        q[j] = o;
    }
}

extern "C" void kernel_launch(void* const* d_in, const int* in_sizes, int n_in,
                              void* d_out, int out_size, void* d_ws, size_t ws_size,
                              hipStream_t stream) {
    const float* x   = (const float*)d_in[0];
    const int*   ei  = (const int*)d_in[1];
    const float* ew  = (const float*)d_in[2];
    const float* W1  = (const float*)d_in[3];
    const float* b1  = (const float*)d_in[4];
    const float* W2  = (const float*)d_in[5];
    const float* b2  = (const float*)d_in[6];
    float* out = (float*)d_out;

    const int N = in_sizes[0] / 256;   // 100000
    const int E = in_sizes[2];         // 1600000
    const int* src = ei;
    const int* dst = ei + E;

    char* ws = (char*)d_ws;
    size_t off = 0;
    auto take = [&](size_t bytes) -> float* {
        float* p = (float*)(ws + off);
        off += (bytes + 255) & ~(size_t)255;
        return p;
    };
    float* dinv  = take((size_t)N * 4);          // deg -> dinv (in place)
    float* enorm = take((size_t)E * 4);
    float* xw1   = take((size_t)N * 128 * 4);
    float* agg1  = take((size_t)N * 128 * 4);
    float* hw2   = take((size_t)N * 40 * 4);
    float* agg2  = take((size_t)N * 40 * 4);

    hipMemsetAsync(dinv, 0, (size_t)N * 4, stream);

    k_deg<<<(E + 255) / 256, 256, 0, stream>>>(dst, ew, dinv, E);
    k_dinv<<<(N + 255) / 256, 256, 0, stream>>>(dinv, N);
    k_edgenorm<<<(E + 255) / 256, 256, 0, stream>>>(src, dst, ew, dinv, enorm, E);

    k_gemm1<<<(N + 63) / 64, 256, 0, stream>>>(x, W1, dinv, xw1, agg1, N);

    int total1 = E * 32;  // 32 float4-chunks per edge (128 feats)
    int grid1 = min((total1 + 255) / 256, 32768);
    k_scatter<32, 128><<<grid1, 256, 0, stream>>>(src, dst, enorm, xw1, agg1, E);

    k_gemm2<<<(N + 63) / 64, 320, 0, stream>>>(agg1, W2, b1, b2, dinv, hw2, agg2, N);

    int total2 = E * 10;  // 10 float4-chunks per edge (40 feats)
    int grid2 = min((total2 + 255) / 256, 16384);
    k_scatter<10, 40><<<grid2, 256, 0, stream>>>(src, dst, enorm, hw2, agg2, E);

    k_normalize<<<(N + 255) / 256, 256, 0, stream>>>(agg2, out, N);
}

// Round 2
// 682.876 us; speedup vs baseline: 5.8317x; 5.8317x over previous
//
#include <hip/hip_runtime.h>

// ---------------------------------------------------------------------------
// 2-layer GCN forward (PyG GCNConv, add_self_loops, sym-norm), CSR-gather.
//   dinv = rsqrt(segsum(ew,dst)+1)
//   h    = relu( Agg(norm, x@W1) + dinv^2*(x@W1) + b1 )
//   out  = L2norm( Agg(norm, h@W2) + dinv^2*(h@W2) + b2 )
// Aggregation is gather (pull) over a device-built CSR sorted by dst.
// ---------------------------------------------------------------------------

// degree (weighted) + histogram counts in one pass
__global__ void k_deg_hist(const int* __restrict__ dst, const float* __restrict__ ew,
                           float* __restrict__ deg, int* __restrict__ counts, int E) {
    int i = blockIdx.x * 256 + threadIdx.x;
    if (i < E) {
        int d = dst[i];
        unsafeAtomicAdd(&deg[d], ew[i]);
        atomicAdd(&counts[d], 1);
    }
}

__global__ void k_dinv(float* __restrict__ deg, int N) {
    int i = blockIdx.x * 256 + threadIdx.x;
    if (i < N) deg[i] = rsqrtf(deg[i] + 1.0f);   // deg >= 1 (self loop)
}

// single-block exclusive scan of counts[0..N) -> row[0..N], row[N] = total
__launch_bounds__(1024)
__global__ void k_scan(const int* __restrict__ counts, int* __restrict__ row, int N) {
    __shared__ int sums[1024];
    __shared__ int carry_s;
    const int t = threadIdx.x;
    if (t == 0) carry_s = 0;
    __syncthreads();
    for (int base = 0; base < N; base += 4096) {
        int i0 = base + t * 4;
        int c0 = (i0 + 0 < N) ? counts[i0 + 0] : 0;
        int c1 = (i0 + 1 < N) ? counts[i0 + 1] : 0;
        int c2 = (i0 + 2 < N) ? counts[i0 + 2] : 0;
        int c3 = (i0 + 3 < N) ? counts[i0 + 3] : 0;
        int s1 = c0, s2 = s1 + c1, s3 = s2 + c2, s4 = s3 + c3;
        sums[t] = s4;
        __syncthreads();
        for (int off = 1; off < 1024; off <<= 1) {
            int v = (t >= off) ? sums[t - off] : 0;
            __syncthreads();
            sums[t] += v;
            __syncthreads();
        }
        int carry = carry_s;
        int excl = carry + (t ? sums[t - 1] : 0);
        if (i0 + 0 < N) row[i0 + 0] = excl;
        if (i0 + 1 < N) row[i0 + 1] = excl + s1;
        if (i0 + 2 < N) row[i0 + 2] = excl + s2;
        if (i0 + 3 < N) row[i0 + 3] = excl + s3;
        __syncthreads();
        if (t == 1023) carry_s = carry + sums[1023];
        __syncthreads();
    }
    if (t == 0) row[N] = carry_s;
}

// fill CSR entries: (src, norm) pairs grouped by dst
__global__ void k_fill(const int* __restrict__ src, const int* __restrict__ dst,
                       const float* __restrict__ ew, const float* __restrict__ dinv,
                       const int* __restrict__ row, int* __restrict__ cursor,
                       int2* __restrict__ entries, int E) {
    int e = blockIdx.x * 256 + threadIdx.x;
    if (e < E) {
        int s = src[e], d = dst[e];
        float w = dinv[s] * ew[e] * dinv[d];
        int idx = row[d] + atomicAdd(&cursor[d], 1);
        entries[idx] = make_int2(s, __float_as_int(w));
    }
}

// GEMM1: xw1[N,128] = x[N,256] @ W1[256,128]
__launch_bounds__(256)
__global__ void k_gemm1(const float* __restrict__ x, const float* __restrict__ W1,
                        float* __restrict__ xw1, int N) {
    __shared__ float As[64 * 68];
    __shared__ float Bs[64 * 132];
    const int t  = threadIdx.x;
    const int tx = t & 15;
    const int ty = t >> 4;
    const int row0 = blockIdx.x * 64;

    float acc[4][8];
#pragma unroll
    for (int r = 0; r < 4; ++r)
#pragma unroll
        for (int c = 0; c < 8; ++c) acc[r][c] = 0.f;

    for (int kt = 0; kt < 4; ++kt) {
#pragma unroll
        for (int i = 0; i < 4; ++i) {
            int flat = t + i * 256;
            int r = flat >> 4, c4 = flat & 15;
            int gr = row0 + r;
            float4 v = make_float4(0.f, 0.f, 0.f, 0.f);
            if (gr < N) v = *(const float4*)(x + (size_t)gr * 256 + kt * 64 + c4 * 4);
            *(float4*)(As + r * 68 + c4 * 4) = v;
        }
#pragma unroll
        for (int i = 0; i < 8; ++i) {
            int flat = t + i * 256;
            int r = flat >> 5, c4 = flat & 31;
            float4 v = *(const float4*)(W1 + (size_t)(kt * 64 + r) * 128 + c4 * 4);
            *(float4*)(Bs + r * 132 + c4 * 4) = v;
        }
        __syncthreads();
#pragma unroll
        for (int k = 0; k < 64; ++k) {
            float a[4];
#pragma unroll
            for (int r = 0; r < 4; ++r) a[r] = As[(ty * 4 + r) * 68 + k];
            float4 b0 = *(const float4*)(Bs + k * 132 + tx * 8);
            float4 b1 = *(const float4*)(Bs + k * 132 + tx * 8 + 4);
#pragma unroll
            for (int r = 0; r < 4; ++r) {
                acc[r][0] += a[r] * b0.x; acc[r][1] += a[r] * b0.y;
                acc[r][2] += a[r] * b0.z; acc[r][3] += a[r] * b0.w;
                acc[r][4] += a[r] * b1.x; acc[r][5] += a[r] * b1.y;
                acc[r][6] += a[r] * b1.z; acc[r][7] += a[r] * b1.w;
            }
        }
        __syncthreads();
    }
#pragma unroll
    for (int r = 0; r < 4; ++r) {
        int gr = row0 + ty * 4 + r;
        if (gr >= N) continue;
        float* xp = xw1 + (size_t)gr * 128 + tx * 8;
        *(float4*)(xp)     = make_float4(acc[r][0], acc[r][1], acc[r][2], acc[r][3]);
        *(float4*)(xp + 4) = make_float4(acc[r][4], acc[r][5], acc[r][6], acc[r][7]);
    }
}

// gather layer 1: agg1[n] = dinv^2[n]*xw1[n] + sum_e w_e * xw1[src_e]
// 32 lanes per node, one float4 per lane (128 feats)
__launch_bounds__(256)
__global__ void k_gather1(const float* __restrict__ xw1, const int2* __restrict__ entries,
                          const int* __restrict__ row, const float* __restrict__ dinv,
                          float* __restrict__ agg1, int N) {
    int g = (blockIdx.x * 256 + threadIdx.x) >> 5;   // node
    if (g >= N) return;
    int j = threadIdx.x & 31;                        // float4 index
    float di = dinv[g];
    float d2 = di * di;
    float4 acc = *(const float4*)(xw1 + (size_t)g * 128 + j * 4);
    acc.x *= d2; acc.y *= d2; acc.z *= d2; acc.w *= d2;
    int beg = row[g], end = row[g + 1];
    for (int e = beg; e < end; ++e) {
        int2 ent = entries[e];
        float w = __int_as_float(ent.y);
        float4 v = *(const float4*)(xw1 + (size_t)ent.x * 128 + j * 4);
        acc.x += w * v.x; acc.y += w * v.y; acc.z += w * v.z; acc.w += w * v.w;
    }
    *(float4*)(agg1 + (size_t)g * 128 + j * 4) = acc;
}

// GEMM2: h = relu(agg1 + b1); hw2[N,40] = h @ W2[128,40]
__launch_bounds__(320)
__global__ void k_gemm2(const float* __restrict__ agg1, const float* __restrict__ W2,
                        const float* __restrict__ b1, float* __restrict__ hw2, int N) {
    __shared__ float As[64 * 132];
    __shared__ float Bs[128 * 40];
    const int t = threadIdx.x;
    const int row0 = blockIdx.x * 64;

    for (int flat = t; flat < 128 * 40; flat += 320) Bs[flat] = W2[flat];

#pragma unroll
    for (int i = 0; i < 7; ++i) {
        int flat = t + i * 320;
        if (flat < 2048) {
            int r = flat >> 5, c4 = flat & 31;
            int gr = row0 + r;
            float4 v = make_float4(0.f, 0.f, 0.f, 0.f);
            if (gr < N) {
                v = *(const float4*)(agg1 + (size_t)gr * 128 + c4 * 4);
                float4 bb = *(const float4*)(b1 + c4 * 4);
                v.x = fmaxf(v.x + bb.x, 0.f);
                v.y = fmaxf(v.y + bb.y, 0.f);
                v.z = fmaxf(v.z + bb.z, 0.f);
                v.w = fmaxf(v.w + bb.w, 0.f);
            }
            *(float4*)(As + r * 132 + c4 * 4) = v;
        }
    }
    __syncthreads();

    const int tx = t % 40;
    const int ty = t / 40;
    float acc[8];
#pragma unroll
    for (int r = 0; r < 8; ++r) acc[r] = 0.f;
    for (int k = 0; k < 128; ++k) {
        float b = Bs[k * 40 + tx];
#pragma unroll
        for (int r = 0; r < 8; ++r) acc[r] += As[(ty * 8 + r) * 132 + k] * b;
    }
#pragma unroll
    for (int r = 0; r < 8; ++r) {
        int gr = row0 + ty * 8 + r;
        if (gr < N) hw2[(size_t)gr * 40 + tx] = acc[r];
    }
}

// gather layer 2 + bias + fused L2 normalize -> out
// 8 lanes per node; lane l owns cols {l, l+8, l+16, l+24, l+32}
__launch_bounds__(256)
__global__ void k_gather2(const float* __restrict__ hw2, const int2* __restrict__ entries,
                          const int* __restrict__ row, const float* __restrict__ dinv,
                          const float* __restrict__ b2, float* __restrict__ out, int N) {
    int g = (blockIdx.x * 256 + threadIdx.x) >> 3;   // node
    if (g >= N) return;
    int l = threadIdx.x & 7;
    float di = dinv[g];
    float d2 = di * di;
    float acc[5];
    const float* hn = hw2 + (size_t)g * 40;
#pragma unroll
    for (int k = 0; k < 5; ++k) acc[k] = d2 * hn[l + 8 * k] + b2[l + 8 * k];
    int beg = row[g], end = row[g + 1];
    for (int e = beg; e < end; ++e) {
        int2 ent = entries[e];
        float w = __int_as_float(ent.y);
        const float* hr = hw2 + (size_t)ent.x * 40;
#pragma unroll
        for (int k = 0; k < 5; ++k) acc[k] += w * hr[l + 8 * k];
    }
    float ss = 0.f;
#pragma unroll
    for (int k = 0; k < 5; ++k) ss += acc[k] * acc[k];
    ss += __shfl_xor(ss, 1);
    ss += __shfl_xor(ss, 2);
    ss += __shfl_xor(ss, 4);
    float inv = 1.f / fmaxf(sqrtf(ss), 1e-12f);
#pragma unroll
    for (int k = 0; k < 5; ++k) out[(size_t)g * 40 + l + 8 * k] = acc[k] * inv;
}

extern "C" void kernel_launch(void* const* d_in, const int* in_sizes, int n_in,
                              void* d_out, int out_size, void* d_ws, size_t ws_size,
                              hipStream_t stream) {
    const float* x   = (const float*)d_in[0];
    const int*   ei  = (const int*)d_in[1];
    const float* ew  = (const float*)d_in[2];
    const float* W1  = (const float*)d_in[3];
    const float* b1  = (const float*)d_in[4];
    const float* W2  = (const float*)d_in[5];
    const float* b2  = (const float*)d_in[6];
    float* out = (float*)d_out;

    const int N = in_sizes[0] / 256;   // 100000
    const int E = in_sizes[2];         // 1600000
    const int* src = ei;
    const int* dst = ei + E;

    char* ws = (char*)d_ws;
    size_t off = 0;
    auto take = [&](size_t bytes) -> void* {
        void* p = (void*)(ws + off);
        off += (bytes + 255) & ~(size_t)255;
        return p;
    };
    float* dinv    = (float*)take((size_t)N * 4);          // deg -> dinv in place
    int*   counts  = (int*)take((size_t)(N + 1) * 4);      // histogram, later cursor
    int*   rowp    = (int*)take((size_t)(N + 1) * 4);      // CSR row offsets
    int2*  entries = (int2*)take((size_t)E * 8);           // (src, norm) by dst
    float* xw1     = (float*)take((size_t)N * 128 * 4);
    float* agg1    = (float*)take((size_t)N * 128 * 4);
    float* hw2     = (float*)take((size_t)N * 40 * 4);

    hipMemsetAsync(dinv, 0, (size_t)N * 4, stream);
    hipMemsetAsync(counts, 0, (size_t)(N + 1) * 4, stream);

    k_deg_hist<<<(E + 255) / 256, 256, 0, stream>>>(dst, ew, dinv, counts, E);
    k_dinv<<<(N + 255) / 256, 256, 0, stream>>>(dinv, N);
    k_scan<<<1, 1024, 0, stream>>>(counts, rowp, N);
    hipMemsetAsync(counts, 0, (size_t)(N + 1) * 4, stream);   // reuse as cursor
    k_fill<<<(E + 255) / 256, 256, 0, stream>>>(src, dst, ew, dinv, rowp, counts, entries, E);

    k_gemm1<<<(N + 63) / 64, 256, 0, stream>>>(x, W1, xw1, N);
    k_gather1<<<(N * 32 + 255) / 256, 256, 0, stream>>>(xw1, entries, rowp, dinv, agg1, N);
    k_gemm2<<<(N + 63) / 64, 320, 0, stream>>>(agg1, W2, b1, hw2, N);
    k_gather2<<<(N * 8 + 255) / 256, 256, 0, stream>>>(hw2, entries, rowp, dinv, b2, out, N);
}

// Round 3
// 476.057 us; speedup vs baseline: 8.3653x; 1.4344x over previous
//
#include <hip/hip_runtime.h>

// ---------------------------------------------------------------------------
// 2-layer GCN forward (PyG GCNConv, add_self_loops, sym-norm), CSR-gather.
//   dinv = rsqrt(segsum(ew,dst)+1)
//   h    = relu( Agg(norm, x@W1) + dinv^2*(x@W1) + b1 )
//   out  = L2norm( Agg(norm, h@W2) + dinv^2*(h@W2) + b2 )
// CSR built with ONE 64-bit atomic per edge: packed[d] += (1<<32)|fix(ew),
// whose return value gives both deg accumulation and the edge's rank.
// ---------------------------------------------------------------------------

#define FIXSCALE 4194304.0f   // 2^22; deg sum < 2^31/2^22 = 512, plenty

__global__ void k_deg_hist(const int* __restrict__ dst, const float* __restrict__ ew,
                           unsigned long long* __restrict__ packed,
                           int* __restrict__ rank, int E) {
    int i = blockIdx.x * 256 + threadIdx.x;
    if (i < E) {
        int d = dst[i];
        unsigned long long v = (1ULL << 32) |
            (unsigned long long)(unsigned)__float2uint_rn(ew[i] * FIXSCALE);
        unsigned long long old = atomicAdd(&packed[d], v);
        rank[i] = (int)(old >> 32);
    }
}

// dinv from packed lo32; per-block count totals from hi32
__launch_bounds__(256)
__global__ void k_prep(const unsigned long long* __restrict__ packed,
                       float* __restrict__ dinv, int* __restrict__ blkTot, int N) {
    __shared__ int red[256];
    int t = threadIdx.x;
    int i = blockIdx.x * 256 + t;
    int cnt = 0;
    if (i < N) {
        unsigned long long p = packed[i];
        cnt = (int)(p >> 32);
        dinv[i] = rsqrtf((float)(unsigned)(p & 0xffffffffULL) * (1.0f / FIXSCALE) + 1.0f);
    }
    red[t] = cnt;
    __syncthreads();
#pragma unroll
    for (int off = 128; off > 0; off >>= 1) {
        if (t < off) red[t] += red[t + off];
        __syncthreads();
    }
    if (t == 0) blkTot[blockIdx.x] = red[0];
}

// single block: exclusive scan of per-block totals (NB <= 512)
__launch_bounds__(512)
__global__ void k_scanblk(const int* __restrict__ blkTot, int* __restrict__ blkOff,
                          int* __restrict__ rowp, int NB, int N, int E) {
    __shared__ int s[512];
    int t = threadIdx.x;
    int v = (t < NB) ? blkTot[t] : 0;
    s[t] = v;
    __syncthreads();
    for (int off = 1; off < 512; off <<= 1) {
        int u = (t >= off) ? s[t - off] : 0;
        __syncthreads();
        s[t] += u;
        __syncthreads();
    }
    if (t < NB) blkOff[t] = s[t] - v;
    if (t == 0) rowp[N] = E;
}

// rowp[i] = blkOff[b] + exclusive_scan_within_block(counts)
__launch_bounds__(256)
__global__ void k_rowp(const unsigned long long* __restrict__ packed,
                       const int* __restrict__ blkOff, int* __restrict__ rowp, int N) {
    __shared__ int s[256];
    int t = threadIdx.x;
    int i = blockIdx.x * 256 + t;
    int cnt = (i < N) ? (int)(packed[i] >> 32) : 0;
    s[t] = cnt;
    __syncthreads();
    for (int off = 1; off < 256; off <<= 1) {
        int u = (t >= off) ? s[t - off] : 0;
        __syncthreads();
        s[t] += u;
        __syncthreads();
    }
    if (i < N) rowp[i] = blkOff[blockIdx.x] + s[t] - cnt;
}

// atomic-free CSR fill: slot = rowp[dst] + rank
__global__ void k_fill(const int* __restrict__ src, const int* __restrict__ dst,
                       const float* __restrict__ ew, const int* __restrict__ rank,
                       const float* __restrict__ dinv, const int* __restrict__ rowp,
                       int2* __restrict__ entries, int E) {
    int e = blockIdx.x * 256 + threadIdx.x;
    if (e < E) {
        int s = src[e], d = dst[e];
        float w = dinv[s] * ew[e] * dinv[d];
        entries[rowp[d] + rank[e]] = make_int2(s, __float_as_int(w));
    }
}

// GEMM1: xw1[N,128] = x[N,256] @ W1[256,128]
__launch_bounds__(256)
__global__ void k_gemm1(const float* __restrict__ x, const float* __restrict__ W1,
                        float* __restrict__ xw1, int N) {
    __shared__ float As[64 * 68];
    __shared__ float Bs[64 * 132];
    const int t  = threadIdx.x;
    const int tx = t & 15;
    const int ty = t >> 4;
    const int row0 = blockIdx.x * 64;

    float acc[4][8];
#pragma unroll
    for (int r = 0; r < 4; ++r)
#pragma unroll
        for (int c = 0; c < 8; ++c) acc[r][c] = 0.f;

    for (int kt = 0; kt < 4; ++kt) {
#pragma unroll
        for (int i = 0; i < 4; ++i) {
            int flat = t + i * 256;
            int r = flat >> 4, c4 = flat & 15;
            int gr = row0 + r;
            float4 v = make_float4(0.f, 0.f, 0.f, 0.f);
            if (gr < N) v = *(const float4*)(x + (size_t)gr * 256 + kt * 64 + c4 * 4);
            *(float4*)(As + r * 68 + c4 * 4) = v;
        }
#pragma unroll
        for (int i = 0; i < 8; ++i) {
            int flat = t + i * 256;
            int r = flat >> 5, c4 = flat & 31;
            float4 v = *(const float4*)(W1 + (size_t)(kt * 64 + r) * 128 + c4 * 4);
            *(float4*)(Bs + r * 132 + c4 * 4) = v;
        }
        __syncthreads();
#pragma unroll
        for (int k = 0; k < 64; ++k) {
            float a[4];
#pragma unroll
            for (int r = 0; r < 4; ++r) a[r] = As[(ty * 4 + r) * 68 + k];
            float4 b0 = *(const float4*)(Bs + k * 132 + tx * 8);
            float4 b1 = *(const float4*)(Bs + k * 132 + tx * 8 + 4);
#pragma unroll
            for (int r = 0; r < 4; ++r) {
                acc[r][0] += a[r] * b0.x; acc[r][1] += a[r] * b0.y;
                acc[r][2] += a[r] * b0.z; acc[r][3] += a[r] * b0.w;
                acc[r][4] += a[r] * b1.x; acc[r][5] += a[r] * b1.y;
                acc[r][6] += a[r] * b1.z; acc[r][7] += a[r] * b1.w;
            }
        }
        __syncthreads();
    }
#pragma unroll
    for (int r = 0; r < 4; ++r) {
        int gr = row0 + ty * 4 + r;
        if (gr >= N) continue;
        float* xp = xw1 + (size_t)gr * 128 + tx * 8;
        *(float4*)(xp)     = make_float4(acc[r][0], acc[r][1], acc[r][2], acc[r][3]);
        *(float4*)(xp + 4) = make_float4(acc[r][4], acc[r][5], acc[r][6], acc[r][7]);
    }
}

// gather layer 1: agg1[n] = dinv^2[n]*xw1[n] + sum_e w_e * xw1[src_e]
__launch_bounds__(256)
__global__ void k_gather1(const float* __restrict__ xw1, const int2* __restrict__ entries,
                          const int* __restrict__ row, const float* __restrict__ dinv,
                          float* __restrict__ agg1, int N) {
    int g = (blockIdx.x * 256 + threadIdx.x) >> 5;   // node
    if (g >= N) return;
    int j = threadIdx.x & 31;                        // float4 index
    float di = dinv[g];
    float d2 = di * di;
    float4 acc = *(const float4*)(xw1 + (size_t)g * 128 + j * 4);
    acc.x *= d2; acc.y *= d2; acc.z *= d2; acc.w *= d2;
    int beg = row[g], end = row[g + 1];
    for (int e = beg; e < end; ++e) {
        int2 ent = entries[e];
        float w = __int_as_float(ent.y);
        float4 v = *(const float4*)(xw1 + (size_t)ent.x * 128 + j * 4);
        acc.x += w * v.x; acc.y += w * v.y; acc.z += w * v.z; acc.w += w * v.w;
    }
    *(float4*)(agg1 + (size_t)g * 128 + j * 4) = acc;
}

// GEMM2: h = relu(agg1 + b1); hw2[N,40] = h @ W2[128,40]
__launch_bounds__(320)
__global__ void k_gemm2(const float* __restrict__ agg1, const float* __restrict__ W2,
                        const float* __restrict__ b1, float* __restrict__ hw2, int N) {
    __shared__ float As[64 * 132];
    __shared__ float Bs[128 * 40];
    const int t = threadIdx.x;
    const int row0 = blockIdx.x * 64;

    for (int flat = t; flat < 128 * 40; flat += 320) Bs[flat] = W2[flat];

#pragma unroll
    for (int i = 0; i < 7; ++i) {
        int flat = t + i * 320;
        if (flat < 2048) {
            int r = flat >> 5, c4 = flat & 31;
            int gr = row0 + r;
            float4 v = make_float4(0.f, 0.f, 0.f, 0.f);
            if (gr < N) {
                v = *(const float4*)(agg1 + (size_t)gr * 128 + c4 * 4);
                float4 bb = *(const float4*)(b1 + c4 * 4);
                v.x = fmaxf(v.x + bb.x, 0.f);
                v.y = fmaxf(v.y + bb.y, 0.f);
                v.z = fmaxf(v.z + bb.z, 0.f);
                v.w = fmaxf(v.w + bb.w, 0.f);
            }
            *(float4*)(As + r * 132 + c4 * 4) = v;
        }
    }
    __syncthreads();

    const int tx = t % 40;
    const int ty = t / 40;
    float acc[8];
#pragma unroll
    for (int r = 0; r < 8; ++r) acc[r] = 0.f;
    for (int k = 0; k < 128; ++k) {
        float b = Bs[k * 40 + tx];
#pragma unroll
        for (int r = 0; r < 8; ++r) acc[r] += As[(ty * 8 + r) * 132 + k] * b;
    }
#pragma unroll
    for (int r = 0; r < 8; ++r) {
        int gr = row0 + ty * 8 + r;
        if (gr < N) hw2[(size_t)gr * 40 + tx] = acc[r];
    }
}

// gather layer 2 + bias + fused L2 normalize -> out
__launch_bounds__(256)
__global__ void k_gather2(const float* __restrict__ hw2, const int2* __restrict__ entries,
                          const int* __restrict__ row, const float* __restrict__ dinv,
                          const float* __restrict__ b2, float* __restrict__ out, int N) {
    int g = (blockIdx.x * 256 + threadIdx.x) >> 3;   // node
    if (g >= N) return;
    int l = threadIdx.x & 7;
    float di = dinv[g];
    float d2 = di * di;
    float acc[5];
    const float* hn = hw2 + (size_t)g * 40;
#pragma unroll
    for (int k = 0; k < 5; ++k) acc[k] = d2 * hn[l + 8 * k] + b2[l + 8 * k];
    int beg = row[g], end = row[g + 1];
    for (int e = beg; e < end; ++e) {
        int2 ent = entries[e];
        float w = __int_as_float(ent.y);
        const float* hr = hw2 + (size_t)ent.x * 40;
#pragma unroll
        for (int k = 0; k < 5; ++k) acc[k] += w * hr[l + 8 * k];
    }
    float ss = 0.f;
#pragma unroll
    for (int k = 0; k < 5; ++k) ss += acc[k] * acc[k];
    ss += __shfl_xor(ss, 1);
    ss += __shfl_xor(ss, 2);
    ss += __shfl_xor(ss, 4);
    float inv = 1.f / fmaxf(sqrtf(ss), 1e-12f);
#pragma unroll
    for (int k = 0; k < 5; ++k) out[(size_t)g * 40 + l + 8 * k] = acc[k] * inv;
}

extern "C" void kernel_launch(void* const* d_in, const int* in_sizes, int n_in,
                              void* d_out, int out_size, void* d_ws, size_t ws_size,
                              hipStream_t stream) {
    const float* x   = (const float*)d_in[0];
    const int*   ei  = (const int*)d_in[1];
    const float* ew  = (const float*)d_in[2];
    const float* W1  = (const float*)d_in[3];
    const float* b1  = (const float*)d_in[4];
    const float* W2  = (const float*)d_in[5];
    const float* b2  = (const float*)d_in[6];
    float* out = (float*)d_out;

    const int N = in_sizes[0] / 256;   // 100000
    const int E = in_sizes[2];         // 1600000
    const int* src = ei;
    const int* dst = ei + E;
    const int NB = (N + 255) / 256;    // 391 scan blocks

    char* ws = (char*)d_ws;
    size_t off = 0;
    auto take = [&](size_t bytes) -> void* {
        void* p = (void*)(ws + off);
        off += (bytes + 255) & ~(size_t)255;
        return p;
    };
    unsigned long long* packed = (unsigned long long*)take((size_t)N * 8);
    int*   rank    = (int*)take((size_t)E * 4);
    float* dinv    = (float*)take((size_t)N * 4);
    int*   blkTot  = (int*)take((size_t)NB * 4);
    int*   blkOff  = (int*)take((size_t)NB * 4);
    int*   rowp    = (int*)take((size_t)(N + 1) * 4);
    int2*  entries = (int2*)take((size_t)E * 8);
    float* xw1     = (float*)take((size_t)N * 128 * 4);
    float* agg1    = (float*)take((size_t)N * 128 * 4);
    float* hw2     = (float*)take((size_t)N * 40 * 4);

    hipMemsetAsync(packed, 0, (size_t)N * 8, stream);

    k_deg_hist<<<(E + 255) / 256, 256, 0, stream>>>(dst, ew, packed, rank, E);
    k_prep<<<NB, 256, 0, stream>>>(packed, dinv, blkTot, N);
    k_scanblk<<<1, 512, 0, stream>>>(blkTot, blkOff, rowp, NB, N, E);
    k_rowp<<<NB, 256, 0, stream>>>(packed, blkOff, rowp, N);
    k_fill<<<(E + 255) / 256, 256, 0, stream>>>(src, dst, ew, rank, dinv, rowp, entries, E);

    // GEMM1 can run concurrently-independent of CSR build ordering on the
    // same stream; sequence is fine either way.
    k_gemm1<<<(N + 63) / 64, 256, 0, stream>>>(x, W1, xw1, N);
    k_gather1<<<(N * 32 + 255) / 256, 256, 0, stream>>>(xw1, entries, rowp, dinv, agg1, N);
    k_gemm2<<<(N + 63) / 64, 320, 0, stream>>>(agg1, W2, b1, hw2, N);
    k_gather2<<<(N * 8 + 255) / 256, 256, 0, stream>>>(hw2, entries, rowp, dinv, b2, out, N);
}

// Round 4
// 435.358 us; speedup vs baseline: 9.1473x; 1.0935x over previous
//
#include <hip/hip_runtime.h>

// ---------------------------------------------------------------------------
// 2-layer GCN forward (PyG GCNConv, add_self_loops, sym-norm), CSR-gather.
//   dinv = rsqrt(segsum(ew,dst)+1)
//   h    = relu( Agg(norm, x@W1) + dinv^2*(x@W1) + b1 )
//   out  = L2norm( Agg(norm, h@W2) + dinv^2*(h@W2) + b2 )
// GEMM1 uses bf16 MFMA with hi/lo split precision (f32-equivalent accuracy).
// ---------------------------------------------------------------------------

typedef unsigned short u16;
typedef __attribute__((ext_vector_type(8))) short short8;
typedef __attribute__((ext_vector_type(4))) float f32x4;

#define FIXSCALE 4194304.0f   // 2^22

static __device__ inline u16 f2bf(float f) {            // RNE f32 -> bf16 bits
    unsigned u = __float_as_uint(f);
    return (u16)((u + 0x7fffu + ((u >> 16) & 1u)) >> 16);
}
static __device__ inline float bf2f(u16 h) { return __uint_as_float(((unsigned)h) << 16); }

__global__ void k_deg_hist(const int* __restrict__ dst, const float* __restrict__ ew,
                           unsigned long long* __restrict__ packed,
                           int* __restrict__ rank, int E) {
    int i = blockIdx.x * 256 + threadIdx.x;
    if (i < E) {
        int d = dst[i];
        unsigned long long v = (1ULL << 32) |
            (unsigned long long)(unsigned)__float2uint_rn(ew[i] * FIXSCALE);
        unsigned long long old = atomicAdd(&packed[d], v);
        rank[i] = (int)(old >> 32);
    }
}

__launch_bounds__(256)
__global__ void k_prep(const unsigned long long* __restrict__ packed,
                       float* __restrict__ dinv, int* __restrict__ blkTot, int N) {
    __shared__ int red[256];
    int t = threadIdx.x;
    int i = blockIdx.x * 256 + t;
    int cnt = 0;
    if (i < N) {
        unsigned long long p = packed[i];
        cnt = (int)(p >> 32);
        dinv[i] = rsqrtf((float)(unsigned)(p & 0xffffffffULL) * (1.0f / FIXSCALE) + 1.0f);
    }
    red[t] = cnt;
    __syncthreads();
#pragma unroll
    for (int off = 128; off > 0; off >>= 1) {
        if (t < off) red[t] += red[t + off];
        __syncthreads();
    }
    if (t == 0) blkTot[blockIdx.x] = red[0];
}

__launch_bounds__(512)
__global__ void k_scanblk(const int* __restrict__ blkTot, int* __restrict__ blkOff,
                          int* __restrict__ rowp, int NB, int N, int E) {
    __shared__ int s[512];
    int t = threadIdx.x;
    int v = (t < NB) ? blkTot[t] : 0;
    s[t] = v;
    __syncthreads();
    for (int off = 1; off < 512; off <<= 1) {
        int u = (t >= off) ? s[t - off] : 0;
        __syncthreads();
        s[t] += u;
        __syncthreads();
    }
    if (t < NB) blkOff[t] = s[t] - v;
    if (t == 0) rowp[N] = E;
}

__launch_bounds__(256)
__global__ void k_rowp(const unsigned long long* __restrict__ packed,
                       const int* __restrict__ blkOff, int* __restrict__ rowp, int N) {
    __shared__ int s[256];
    int t = threadIdx.x;
    int i = blockIdx.x * 256 + t;
    int cnt = (i < N) ? (int)(packed[i] >> 32) : 0;
    s[t] = cnt;
    __syncthreads();
    for (int off = 1; off < 256; off <<= 1) {
        int u = (t >= off) ? s[t - off] : 0;
        __syncthreads();
        s[t] += u;
        __syncthreads();
    }
    if (i < N) rowp[i] = blkOff[blockIdx.x] + s[t] - cnt;
}

__global__ void k_fill(const int* __restrict__ src, const int* __restrict__ dst,
                       const float* __restrict__ ew, const int* __restrict__ rank,
                       const float* __restrict__ dinv, const int* __restrict__ rowp,
                       int2* __restrict__ entries, int E) {
    int e = blockIdx.x * 256 + threadIdx.x;
    if (e < E) {
        int s = src[e], d = dst[e];
        float w = dinv[s] * ew[e] * dinv[d];
        entries[rowp[d] + rank[e]] = make_int2(s, __float_as_int(w));
    }
}

// W1[256,128] f32 -> Wt_hi/Wt_lo[128,256] bf16 (transposed, split precision)
__global__ void k_wsplit(const float* __restrict__ W1, u16* __restrict__ wt_hi,
                         u16* __restrict__ wt_lo) {
    int idx = blockIdx.x * 256 + threadIdx.x;
    if (idx < 256 * 128) {
        int n = idx & 127, k = idx >> 7;
        float f = W1[idx];
        u16 h = f2bf(f);
        wt_hi[n * 256 + k] = h;
        wt_lo[n * 256 + k] = f2bf(f - bf2f(h));
    }
}

// GEMM1: xw1[N,128] = x[N,256] @ W1  via bf16 MFMA, split precision.
// Block: 128 rows x 128 cols, 4 waves (each 32 rows), K-step 32.
__launch_bounds__(256)
__global__ void k_gemm1(const float* __restrict__ x, const u16* __restrict__ wt_hi,
                        const u16* __restrict__ wt_lo, float* __restrict__ xw1, int N) {
    __shared__ __align__(16) u16 Ah[128 * 40];
    __shared__ __align__(16) u16 Al[128 * 40];
    __shared__ __align__(16) u16 Bh[128 * 40];
    __shared__ __align__(16) u16 Bl[128 * 40];

    const int t = threadIdx.x;
    const int w = t >> 6;
    const int lane = t & 63;
    const int lrow = lane & 15;
    const int lk = (lane >> 4) * 8;
    const int row0 = blockIdx.x * 128;

    f32x4 acc[2][8] = {};

    for (int kt = 0; kt < 8; ++kt) {
        // stage A (x tile 128x32 f32 -> hi/lo bf16)
#pragma unroll
        for (int i = 0; i < 4; ++i) {
            int flat = t + i * 256;
            int r = flat >> 3, c4 = flat & 7;
            int gr = row0 + r;
            float4 v = make_float4(0.f, 0.f, 0.f, 0.f);
            if (gr < N) v = *(const float4*)(x + (size_t)gr * 256 + kt * 32 + c4 * 4);
            ushort4 vh, vl;
            vh.x = f2bf(v.x); vl.x = f2bf(v.x - bf2f(vh.x));
            vh.y = f2bf(v.y); vl.y = f2bf(v.y - bf2f(vh.y));
            vh.z = f2bf(v.z); vl.z = f2bf(v.z - bf2f(vh.z));
            vh.w = f2bf(v.w); vl.w = f2bf(v.w - bf2f(vh.w));
            *(ushort4*)(Ah + r * 40 + c4 * 4) = vh;
            *(ushort4*)(Al + r * 40 + c4 * 4) = vl;
        }
        // stage B (Wt tiles 128x32 bf16, already split)
#pragma unroll
        for (int i = 0; i < 2; ++i) {
            int flat = t + i * 256;
            int n = flat >> 2, c = flat & 3;
            *(short8*)(Bh + n * 40 + c * 8) =
                *(const short8*)(wt_hi + (size_t)n * 256 + kt * 32 + c * 8);
            *(short8*)(Bl + n * 40 + c * 8) =
                *(const short8*)(wt_lo + (size_t)n * 256 + kt * 32 + c * 8);
        }
        __syncthreads();

        short8 ah0 = *(const short8*)(Ah + (w * 32 + lrow) * 40 + lk);
        short8 ah1 = *(const short8*)(Ah + (w * 32 + 16 + lrow) * 40 + lk);
        short8 al0 = *(const short8*)(Al + (w * 32 + lrow) * 40 + lk);
        short8 al1 = *(const short8*)(Al + (w * 32 + 16 + lrow) * 40 + lk);
#pragma unroll
        for (int ni = 0; ni < 8; ++ni) {
            short8 bh = *(const short8*)(Bh + (ni * 16 + lrow) * 40 + lk);
            short8 bl = *(const short8*)(Bl + (ni * 16 + lrow) * 40 + lk);
            acc[0][ni] = __builtin_amdgcn_mfma_f32_16x16x32_bf16(ah0, bh, acc[0][ni], 0, 0, 0);
            acc[1][ni] = __builtin_amdgcn_mfma_f32_16x16x32_bf16(ah1, bh, acc[1][ni], 0, 0, 0);
            acc[0][ni] = __builtin_amdgcn_mfma_f32_16x16x32_bf16(al0, bh, acc[0][ni], 0, 0, 0);
            acc[1][ni] = __builtin_amdgcn_mfma_f32_16x16x32_bf16(al1, bh, acc[1][ni], 0, 0, 0);
            acc[0][ni] = __builtin_amdgcn_mfma_f32_16x16x32_bf16(ah0, bl, acc[0][ni], 0, 0, 0);
            acc[1][ni] = __builtin_amdgcn_mfma_f32_16x16x32_bf16(ah1, bl, acc[1][ni], 0, 0, 0);
        }
        __syncthreads();
    }

    // epilogue: D frag layout col=lane&15, row=(lane>>4)*4+reg (m89-verified)
#pragma unroll
    for (int mi = 0; mi < 2; ++mi) {
        int rbase = row0 + w * 32 + mi * 16 + (lane >> 4) * 4;
#pragma unroll
        for (int r = 0; r < 4; ++r) {
            int gr = rbase + r;
            if (gr < N) {
                float* p = xw1 + (size_t)gr * 128 + (lane & 15);
#pragma unroll
                for (int ni = 0; ni < 8; ++ni) p[ni * 16] = acc[mi][ni][r];
            }
        }
    }
}

// gather layer 1: agg1[n] = dinv^2[n]*xw1[n] + sum_e w_e * xw1[src_e]
__launch_bounds__(256)
__global__ void k_gather1(const float* __restrict__ xw1, const int2* __restrict__ entries,
                          const int* __restrict__ row, const float* __restrict__ dinv,
                          float* __restrict__ agg1, int N) {
    int g = (blockIdx.x * 256 + threadIdx.x) >> 5;
    if (g >= N) return;
    int j = threadIdx.x & 31;
    float di = dinv[g];
    float d2 = di * di;
    float4 acc = *(const float4*)(xw1 + (size_t)g * 128 + j * 4);
    acc.x *= d2; acc.y *= d2; acc.z *= d2; acc.w *= d2;
    int beg = row[g], end = row[g + 1];
    for (int e = beg; e < end; ++e) {
        int2 ent = entries[e];
        float w = __int_as_float(ent.y);
        float4 v = *(const float4*)(xw1 + (size_t)ent.x * 128 + j * 4);
        acc.x += w * v.x; acc.y += w * v.y; acc.z += w * v.z; acc.w += w * v.w;
    }
    *(float4*)(agg1 + (size_t)g * 128 + j * 4) = acc;
}

// GEMM2: h = relu(agg1 + b1); hw2[N,40] = h @ W2[128,40]
__launch_bounds__(320)
__global__ void k_gemm2(const float* __restrict__ agg1, const float* __restrict__ W2,
                        const float* __restrict__ b1, float* __restrict__ hw2, int N) {
    __shared__ float As[64 * 132];
    __shared__ float Bs[128 * 40];
    const int t = threadIdx.x;
    const int row0 = blockIdx.x * 64;

    for (int flat = t; flat < 128 * 40; flat += 320) Bs[flat] = W2[flat];

#pragma unroll
    for (int i = 0; i < 7; ++i) {
        int flat = t + i * 320;
        if (flat < 2048) {
            int r = flat >> 5, c4 = flat & 31;
            int gr = row0 + r;
            float4 v = make_float4(0.f, 0.f, 0.f, 0.f);
            if (gr < N) {
                v = *(const float4*)(agg1 + (size_t)gr * 128 + c4 * 4);
                float4 bb = *(const float4*)(b1 + c4 * 4);
                v.x = fmaxf(v.x + bb.x, 0.f);
                v.y = fmaxf(v.y + bb.y, 0.f);
                v.z = fmaxf(v.z + bb.z, 0.f);
                v.w = fmaxf(v.w + bb.w, 0.f);
            }
            *(float4*)(As + r * 132 + c4 * 4) = v;
        }
    }
    __syncthreads();

    const int tx = t % 40;
    const int ty = t / 40;
    float acc[8];
#pragma unroll
    for (int r = 0; r < 8; ++r) acc[r] = 0.f;
    for (int k = 0; k < 128; ++k) {
        float b = Bs[k * 40 + tx];
#pragma unroll
        for (int r = 0; r < 8; ++r) acc[r] += As[(ty * 8 + r) * 132 + k] * b;
    }
#pragma unroll
    for (int r = 0; r < 8; ++r) {
        int gr = row0 + ty * 8 + r;
        if (gr < N) hw2[(size_t)gr * 40 + tx] = acc[r];
    }
}

// gather layer 2 + bias + fused L2 normalize -> out
__launch_bounds__(256)
__global__ void k_gather2(const float* __restrict__ hw2, const int2* __restrict__ entries,
                          const int* __restrict__ row, const float* __restrict__ dinv,
                          const float* __restrict__ b2, float* __restrict__ out, int N) {
    int g = (blockIdx.x * 256 + threadIdx.x) >> 3;
    if (g >= N) return;
    int l = threadIdx.x & 7;
    float di = dinv[g];
    float d2 = di * di;
    float acc[5];
    const float* hn = hw2 + (size_t)g * 40;
#pragma unroll
    for (int k = 0; k < 5; ++k) acc[k] = d2 * hn[l + 8 * k] + b2[l + 8 * k];
    int beg = row[g], end = row[g + 1];
    for (int e = beg; e < end; ++e) {
        int2 ent = entries[e];
        float w = __int_as_float(ent.y);
        const float* hr = hw2 + (size_t)ent.x * 40;
#pragma unroll
        for (int k = 0; k < 5; ++k) acc[k] += w * hr[l + 8 * k];
    }
    float ss = 0.f;
#pragma unroll
    for (int k = 0; k < 5; ++k) ss += acc[k] * acc[k];
    ss += __shfl_xor(ss, 1);
    ss += __shfl_xor(ss, 2);
    ss += __shfl_xor(ss, 4);
    float inv = 1.f / fmaxf(sqrtf(ss), 1e-12f);
#pragma unroll
    for (int k = 0; k < 5; ++k) out[(size_t)g * 40 + l + 8 * k] = acc[k] * inv;
}

extern "C" void kernel_launch(void* const* d_in, const int* in_sizes, int n_in,
                              void* d_out, int out_size, void* d_ws, size_t ws_size,
                              hipStream_t stream) {
    const float* x   = (const float*)d_in[0];
    const int*   ei  = (const int*)d_in[1];
    const float* ew  = (const float*)d_in[2];
    const float* W1  = (const float*)d_in[3];
    const float* b1  = (const float*)d_in[4];
    const float* W2  = (const float*)d_in[5];
    const float* b2  = (const float*)d_in[6];
    float* out = (float*)d_out;

    const int N = in_sizes[0] / 256;   // 100000
    const int E = in_sizes[2];         // 1600000
    const int* src = ei;
    const int* dst = ei + E;
    const int NB = (N + 255) / 256;

    char* ws = (char*)d_ws;
    size_t off = 0;
    auto take = [&](size_t bytes) -> void* {
        void* p = (void*)(ws + off);
        off += (bytes + 255) & ~(size_t)255;
        return p;
    };
    unsigned long long* packed = (unsigned long long*)take((size_t)N * 8);
    int*   rank    = (int*)take((size_t)E * 4);
    float* dinv    = (float*)take((size_t)N * 4);
    int*   blkTot  = (int*)take((size_t)NB * 4);
    int*   blkOff  = (int*)take((size_t)NB * 4);
    int*   rowp    = (int*)take((size_t)(N + 1) * 4);
    int2*  entries = (int2*)take((size_t)E * 8);
    u16*   wt_hi   = (u16*)take((size_t)128 * 256 * 2);
    u16*   wt_lo   = (u16*)take((size_t)128 * 256 * 2);
    float* xw1     = (float*)take((size_t)N * 128 * 4);
    float* agg1    = (float*)take((size_t)N * 128 * 4);
    float* hw2     = (float*)take((size_t)N * 40 * 4);

    hipMemsetAsync(packed, 0, (size_t)N * 8, stream);

    k_deg_hist<<<(E + 255) / 256, 256, 0, stream>>>(dst, ew, packed, rank, E);
    k_prep<<<NB, 256, 0, stream>>>(packed, dinv, blkTot, N);
    k_scanblk<<<1, 512, 0, stream>>>(blkTot, blkOff, rowp, NB, N, E);
    k_rowp<<<NB, 256, 0, stream>>>(packed, blkOff, rowp, N);
    k_fill<<<(E + 255) / 256, 256, 0, stream>>>(src, dst, ew, rank, dinv, rowp, entries, E);

    k_wsplit<<<(256 * 128 + 255) / 256, 256, 0, stream>>>(W1, wt_hi, wt_lo);
    k_gemm1<<<(N + 127) / 128, 256, 0, stream>>>(x, wt_hi, wt_lo, xw1, N);
    k_gather1<<<(N * 32 + 255) / 256, 256, 0, stream>>>(xw1, entries, rowp, dinv, agg1, N);
    k_gemm2<<<(N + 63) / 64, 320, 0, stream>>>(agg1, W2, b1, hw2, N);
    k_gather2<<<(N * 8 + 255) / 256, 256, 0, stream>>>(hw2, entries, rowp, dinv, b2, out, N);
}

// Round 5
// 356.602 us; speedup vs baseline: 11.1675x; 1.2208x over previous
//
#include <hip/hip_runtime.h>

// ---------------------------------------------------------------------------
// 2-layer GCN forward (PyG GCNConv, add_self_loops, sym-norm), CSR-gather.
//   dinv = rsqrt(segsum(ew,dst)+1)
//   h    = relu( Agg(norm, x@W1) + dinv^2*(x@W1) + b1 )
//   out  = L2norm( Agg(norm, h@W2) + dinv^2*(h@W2) + b2 )
// GEMM1: bf16 MFMA, hi/lo split precision. xw1 stored bf16 (halves gather BW).
// ---------------------------------------------------------------------------

typedef unsigned short u16;
typedef __attribute__((ext_vector_type(8))) short short8;
typedef __attribute__((ext_vector_type(4))) float f32x4;

#define FIXSCALE 4194304.0f   // 2^22

static __device__ inline u16 f2bf(float f) {            // RNE f32 -> bf16 bits
    unsigned u = __float_as_uint(f);
    return (u16)((u + 0x7fffu + ((u >> 16) & 1u)) >> 16);
}
static __device__ inline float bf2f(u16 h) { return __uint_as_float(((unsigned)h) << 16); }

__global__ void k_deg_hist(const int* __restrict__ dst, const float* __restrict__ ew,
                           unsigned long long* __restrict__ packed,
                           int* __restrict__ rank, int E) {
    int i = blockIdx.x * 256 + threadIdx.x;
    if (i < E) {
        int d = dst[i];
        unsigned long long v = (1ULL << 32) |
            (unsigned long long)(unsigned)__float2uint_rn(ew[i] * FIXSCALE);
        unsigned long long old = atomicAdd(&packed[d], v);
        rank[i] = (int)(old >> 32);
    }
}

__launch_bounds__(256)
__global__ void k_prep(const unsigned long long* __restrict__ packed,
                       float* __restrict__ dinv, int* __restrict__ blkTot, int N) {
    __shared__ int red[256];
    int t = threadIdx.x;
    int i = blockIdx.x * 256 + t;
    int cnt = 0;
    if (i < N) {
        unsigned long long p = packed[i];
        cnt = (int)(p >> 32);
        dinv[i] = rsqrtf((float)(unsigned)(p & 0xffffffffULL) * (1.0f / FIXSCALE) + 1.0f);
    }
    red[t] = cnt;
    __syncthreads();
#pragma unroll
    for (int off = 128; off > 0; off >>= 1) {
        if (t < off) red[t] += red[t + off];
        __syncthreads();
    }
    if (t == 0) blkTot[blockIdx.x] = red[0];
}

__launch_bounds__(512)
__global__ void k_scanblk(const int* __restrict__ blkTot, int* __restrict__ blkOff,
                          int* __restrict__ rowp, int NB, int N, int E) {
    __shared__ int s[512];
    int t = threadIdx.x;
    int v = (t < NB) ? blkTot[t] : 0;
    s[t] = v;
    __syncthreads();
    for (int off = 1; off < 512; off <<= 1) {
        int u = (t >= off) ? s[t - off] : 0;
        __syncthreads();
        s[t] += u;
        __syncthreads();
    }
    if (t < NB) blkOff[t] = s[t] - v;
    if (t == 0) rowp[N] = E;
}

__launch_bounds__(256)
__global__ void k_rowp(const unsigned long long* __restrict__ packed,
                       const int* __restrict__ blkOff, int* __restrict__ rowp, int N) {
    __shared__ int s[256];
    int t = threadIdx.x;
    int i = blockIdx.x * 256 + t;
    int cnt = (i < N) ? (int)(packed[i] >> 32) : 0;
    s[t] = cnt;
    __syncthreads();
    for (int off = 1; off < 256; off <<= 1) {
        int u = (t >= off) ? s[t - off] : 0;
        __syncthreads();
        s[t] += u;
        __syncthreads();
    }
    if (i < N) rowp[i] = blkOff[blockIdx.x] + s[t] - cnt;
}

__global__ void k_fill(const int* __restrict__ src, const int* __restrict__ dst,
                       const float* __restrict__ ew, const int* __restrict__ rank,
                       const float* __restrict__ dinv, const int* __restrict__ rowp,
                       int2* __restrict__ entries, int E) {
    int e = blockIdx.x * 256 + threadIdx.x;
    if (e < E) {
        int s = src[e], d = dst[e];
        float w = dinv[s] * ew[e] * dinv[d];
        entries[rowp[d] + rank[e]] = make_int2(s, __float_as_int(w));
    }
}

// W1[256,128] f32 -> Wt_hi/Wt_lo[128,256] bf16 (transposed, split precision)
__global__ void k_wsplit(const float* __restrict__ W1, u16* __restrict__ wt_hi,
                         u16* __restrict__ wt_lo) {
    int idx = blockIdx.x * 256 + threadIdx.x;
    if (idx < 256 * 128) {
        int n = idx & 127, k = idx >> 7;
        float f = W1[idx];
        u16 h = f2bf(f);
        wt_hi[n * 256 + k] = h;
        wt_lo[n * 256 + k] = f2bf(f - bf2f(h));
    }
}

// GEMM1: xw1[N,128](bf16) = x[N,256] @ W1  via bf16 MFMA, split precision.
__launch_bounds__(256)
__global__ void k_gemm1(const float* __restrict__ x, const u16* __restrict__ wt_hi,
                        const u16* __restrict__ wt_lo, u16* __restrict__ xw1, int N) {
    __shared__ __align__(16) u16 Ah[128 * 40];
    __shared__ __align__(16) u16 Al[128 * 40];
    __shared__ __align__(16) u16 Bh[128 * 40];
    __shared__ __align__(16) u16 Bl[128 * 40];

    const int t = threadIdx.x;
    const int w = t >> 6;
    const int lane = t & 63;
    const int lrow = lane & 15;
    const int lk = (lane >> 4) * 8;
    const int row0 = blockIdx.x * 128;

    f32x4 acc[2][8] = {};

    for (int kt = 0; kt < 8; ++kt) {
#pragma unroll
        for (int i = 0; i < 4; ++i) {
            int flat = t + i * 256;
            int r = flat >> 3, c4 = flat & 7;
            int gr = row0 + r;
            float4 v = make_float4(0.f, 0.f, 0.f, 0.f);
            if (gr < N) v = *(const float4*)(x + (size_t)gr * 256 + kt * 32 + c4 * 4);
            ushort4 vh, vl;
            vh.x = f2bf(v.x); vl.x = f2bf(v.x - bf2f(vh.x));
            vh.y = f2bf(v.y); vl.y = f2bf(v.y - bf2f(vh.y));
            vh.z = f2bf(v.z); vl.z = f2bf(v.z - bf2f(vh.z));
            vh.w = f2bf(v.w); vl.w = f2bf(v.w - bf2f(vh.w));
            *(ushort4*)(Ah + r * 40 + c4 * 4) = vh;
            *(ushort4*)(Al + r * 40 + c4 * 4) = vl;
        }
#pragma unroll
        for (int i = 0; i < 2; ++i) {
            int flat = t + i * 256;
            int n = flat >> 2, c = flat & 3;
            *(short8*)(Bh + n * 40 + c * 8) =
                *(const short8*)(wt_hi + (size_t)n * 256 + kt * 32 + c * 8);
            *(short8*)(Bl + n * 40 + c * 8) =
                *(const short8*)(wt_lo + (size_t)n * 256 + kt * 32 + c * 8);
        }
        __syncthreads();

        short8 ah0 = *(const short8*)(Ah + (w * 32 + lrow) * 40 + lk);
        short8 ah1 = *(const short8*)(Ah + (w * 32 + 16 + lrow) * 40 + lk);
        short8 al0 = *(const short8*)(Al + (w * 32 + lrow) * 40 + lk);
        short8 al1 = *(const short8*)(Al + (w * 32 + 16 + lrow) * 40 + lk);
#pragma unroll
        for (int ni = 0; ni < 8; ++ni) {
            short8 bh = *(const short8*)(Bh + (ni * 16 + lrow) * 40 + lk);
            short8 bl = *(const short8*)(Bl + (ni * 16 + lrow) * 40 + lk);
            acc[0][ni] = __builtin_amdgcn_mfma_f32_16x16x32_bf16(ah0, bh, acc[0][ni], 0, 0, 0);
            acc[1][ni] = __builtin_amdgcn_mfma_f32_16x16x32_bf16(ah1, bh, acc[1][ni], 0, 0, 0);
            acc[0][ni] = __builtin_amdgcn_mfma_f32_16x16x32_bf16(al0, bh, acc[0][ni], 0, 0, 0);
            acc[1][ni] = __builtin_amdgcn_mfma_f32_16x16x32_bf16(al1, bh, acc[1][ni], 0, 0, 0);
            acc[0][ni] = __builtin_amdgcn_mfma_f32_16x16x32_bf16(ah0, bl, acc[0][ni], 0, 0, 0);
            acc[1][ni] = __builtin_amdgcn_mfma_f32_16x16x32_bf16(ah1, bl, acc[1][ni], 0, 0, 0);
        }
        __syncthreads();
    }

    // D frag: col=lane&15, row=(lane>>4)*4+reg; store bf16
#pragma unroll
    for (int mi = 0; mi < 2; ++mi) {
        int rbase = row0 + w * 32 + mi * 16 + (lane >> 4) * 4;
#pragma unroll
        for (int r = 0; r < 4; ++r) {
            int gr = rbase + r;
            if (gr < N) {
                u16* p = xw1 + (size_t)gr * 128 + (lane & 15);
#pragma unroll
                for (int ni = 0; ni < 8; ++ni) p[ni * 16] = f2bf(acc[mi][ni][r]);
            }
        }
    }
}

// gather layer 1: agg1[n] = dinv^2[n]*xw1[n] + sum_e w_e * xw1[src_e]
// 32 lanes/node, 4 bf16 feats per lane (8B loads), 2-way edge unroll.
__launch_bounds__(256)
__global__ void k_gather1(const u16* __restrict__ xw1, const int2* __restrict__ entries,
                          const int* __restrict__ row, const float* __restrict__ dinv,
                          float* __restrict__ agg1, int N) {
    int g = (blockIdx.x * 256 + threadIdx.x) >> 5;
    if (g >= N) return;
    int j = (threadIdx.x & 31) * 4;                  // feature offset
    float di = dinv[g];
    float d2 = di * di;
    ushort4 sv = *(const ushort4*)(xw1 + (size_t)g * 128 + j);
    float4 acc = make_float4(d2 * bf2f(sv.x), d2 * bf2f(sv.y),
                             d2 * bf2f(sv.z), d2 * bf2f(sv.w));
    int e = row[g], end = row[g + 1];
    for (; e + 2 <= end; e += 2) {
        int2 e0 = entries[e];
        int2 e1 = entries[e + 1];
        ushort4 v0 = *(const ushort4*)(xw1 + (size_t)e0.x * 128 + j);
        ushort4 v1 = *(const ushort4*)(xw1 + (size_t)e1.x * 128 + j);
        float w0 = __int_as_float(e0.y), w1 = __int_as_float(e1.y);
        acc.x += w0 * bf2f(v0.x) + w1 * bf2f(v1.x);
        acc.y += w0 * bf2f(v0.y) + w1 * bf2f(v1.y);
        acc.z += w0 * bf2f(v0.z) + w1 * bf2f(v1.z);
        acc.w += w0 * bf2f(v0.w) + w1 * bf2f(v1.w);
    }
    if (e < end) {
        int2 e0 = entries[e];
        ushort4 v0 = *(const ushort4*)(xw1 + (size_t)e0.x * 128 + j);
        float w0 = __int_as_float(e0.y);
        acc.x += w0 * bf2f(v0.x);
        acc.y += w0 * bf2f(v0.y);
        acc.z += w0 * bf2f(v0.z);
        acc.w += w0 * bf2f(v0.w);
    }
    *(float4*)(agg1 + (size_t)g * 128 + j) = acc;
}

// GEMM2: h = relu(agg1 + b1); hw2[N,40] = h @ W2[128,40]
__launch_bounds__(320)
__global__ void k_gemm2(const float* __restrict__ agg1, const float* __restrict__ W2,
                        const float* __restrict__ b1, float* __restrict__ hw2, int N) {
    __shared__ float As[64 * 132];
    __shared__ float Bs[128 * 40];
    const int t = threadIdx.x;
    const int row0 = blockIdx.x * 64;

    for (int flat = t; flat < 128 * 40; flat += 320) Bs[flat] = W2[flat];

#pragma unroll
    for (int i = 0; i < 7; ++i) {
        int flat = t + i * 320;
        if (flat < 2048) {
            int r = flat >> 5, c4 = flat & 31;
            int gr = row0 + r;
            float4 v = make_float4(0.f, 0.f, 0.f, 0.f);
            if (gr < N) {
                v = *(const float4*)(agg1 + (size_t)gr * 128 + c4 * 4);
                float4 bb = *(const float4*)(b1 + c4 * 4);
                v.x = fmaxf(v.x + bb.x, 0.f);
                v.y = fmaxf(v.y + bb.y, 0.f);
                v.z = fmaxf(v.z + bb.z, 0.f);
                v.w = fmaxf(v.w + bb.w, 0.f);
            }
            *(float4*)(As + r * 132 + c4 * 4) = v;
        }
    }
    __syncthreads();

    const int tx = t % 40;
    const int ty = t / 40;
    float acc[8];
#pragma unroll
    for (int r = 0; r < 8; ++r) acc[r] = 0.f;
    for (int k = 0; k < 128; ++k) {
        float b = Bs[k * 40 + tx];
#pragma unroll
        for (int r = 0; r < 8; ++r) acc[r] += As[(ty * 8 + r) * 132 + k] * b;
    }
#pragma unroll
    for (int r = 0; r < 8; ++r) {
        int gr = row0 + ty * 8 + r;
        if (gr < N) hw2[(size_t)gr * 40 + tx] = acc[r];
    }
}

// gather layer 2 + bias + fused L2 normalize -> out
__launch_bounds__(256)
__global__ void k_gather2(const float* __restrict__ hw2, const int2* __restrict__ entries,
                          const int* __restrict__ row, const float* __restrict__ dinv,
                          const float* __restrict__ b2, float* __restrict__ out, int N) {
    int g = (blockIdx.x * 256 + threadIdx.x) >> 3;
    if (g >= N) return;
    int l = threadIdx.x & 7;
    float di = dinv[g];
    float d2 = di * di;
    float acc[5];
    const float* hn = hw2 + (size_t)g * 40;
#pragma unroll
    for (int k = 0; k < 5; ++k) acc[k] = d2 * hn[l + 8 * k] + b2[l + 8 * k];
    int beg = row[g], end = row[g + 1];
    for (int e = beg; e < end; ++e) {
        int2 ent = entries[e];
        float w = __int_as_float(ent.y);
        const float* hr = hw2 + (size_t)ent.x * 40;
#pragma unroll
        for (int k = 0; k < 5; ++k) acc[k] += w * hr[l + 8 * k];
    }
    float ss = 0.f;
#pragma unroll
    for (int k = 0; k < 5; ++k) ss += acc[k] * acc[k];
    ss += __shfl_xor(ss, 1);
    ss += __shfl_xor(ss, 2);
    ss += __shfl_xor(ss, 4);
    float inv = 1.f / fmaxf(sqrtf(ss), 1e-12f);
#pragma unroll
    for (int k = 0; k < 5; ++k) out[(size_t)g * 40 + l + 8 * k] = acc[k] * inv;
}

extern "C" void kernel_launch(void* const* d_in, const int* in_sizes, int n_in,
                              void* d_out, int out_size, void* d_ws, size_t ws_size,
                              hipStream_t stream) {
    const float* x   = (const float*)d_in[0];
    const int*   ei  = (const int*)d_in[1];
    const float* ew  = (const float*)d_in[2];
    const float* W1  = (const float*)d_in[3];
    const float* b1  = (const float*)d_in[4];
    const float* W2  = (const float*)d_in[5];
    const float* b2  = (const float*)d_in[6];
    float* out = (float*)d_out;

    const int N = in_sizes[0] / 256;   // 100000
    const int E = in_sizes[2];         // 1600000
    const int* src = ei;
    const int* dst = ei + E;
    const int NB = (N + 255) / 256;

    char* ws = (char*)d_ws;
    size_t off = 0;
    auto take = [&](size_t bytes) -> void* {
        void* p = (void*)(ws + off);
        off += (bytes + 255) & ~(size_t)255;
        return p;
    };
    unsigned long long* packed = (unsigned long long*)take((size_t)N * 8);
    int*   rank    = (int*)take((size_t)E * 4);
    float* dinv    = (float*)take((size_t)N * 4);
    int*   blkTot  = (int*)take((size_t)NB * 4);
    int*   blkOff  = (int*)take((size_t)NB * 4);
    int*   rowp    = (int*)take((size_t)(N + 1) * 4);
    int2*  entries = (int2*)take((size_t)E * 8);
    u16*   wt_hi   = (u16*)take((size_t)128 * 256 * 2);
    u16*   wt_lo   = (u16*)take((size_t)128 * 256 * 2);
    u16*   xw1     = (u16*)take((size_t)N * 128 * 2);
    float* agg1    = (float*)take((size_t)N * 128 * 4);
    float* hw2     = (float*)take((size_t)N * 40 * 4);

    hipMemsetAsync(packed, 0, (size_t)N * 8, stream);

    k_deg_hist<<<(E + 255) / 256, 256, 0, stream>>>(dst, ew, packed, rank, E);
    k_prep<<<NB, 256, 0, stream>>>(packed, dinv, blkTot, N);
    k_scanblk<<<1, 512, 0, stream>>>(blkTot, blkOff, rowp, NB, N, E);
    k_rowp<<<NB, 256, 0, stream>>>(packed, blkOff, rowp, N);
    k_fill<<<(E + 255) / 256, 256, 0, stream>>>(src, dst, ew, rank, dinv, rowp, entries, E);

    k_wsplit<<<(256 * 128 + 255) / 256, 256, 0, stream>>>(W1, wt_hi, wt_lo);
    k_gemm1<<<(N + 127) / 128, 256, 0, stream>>>(x, wt_hi, wt_lo, xw1, N);
    k_gather1<<<(N * 32 + 255) / 256, 256, 0, stream>>>(xw1, entries, rowp, dinv, agg1, N);
    k_gemm2<<<(N + 63) / 64, 320, 0, stream>>>(agg1, W2, b1, hw2, N);
    k_gather2<<<(N * 8 + 255) / 256, 256, 0, stream>>>(hw2, entries, rowp, dinv, b2, out, N);
}